// Round 3
// baseline (403.237 us; speedup 1.0000x reference)
//
#include <hip/hip_runtime.h>
#include <math.h>

#define NTHREADS 256
#define NELEM    4096            // H*W
#define EPL      64              // elements per lane (one wave per row)
#define NREP     4               // histogram replicas per region
#define HSTRIDE  260             // %4==0 (b128-aligned reads), %32==4 (replica bank spread)
#define REGION   (NREP * HSTRIDE)     // 1040 uints (region A / region B)
#define WHSIZE   (2 * REGION)         // 2080 uints per wave

// order-preserving float->uint map (ascending)
__device__ __forceinline__ unsigned f2ord(float f) {
    unsigned u = __float_as_uint(f);
    return (u & 0x80000000u) ? ~u : (u | 0x80000000u);
}
__device__ __forceinline__ float ord2f(unsigned k) {
    unsigned u = (k & 0x80000000u) ? (k ^ 0x80000000u) : ~k;
    return __uint_as_float(u);
}

// Wave-level scan over 256 bins (4 bins/lane, NREP replicas) of `region`;
// for each requested rank r, writes {bucket, r_within_bucket} to slot.
// Wave-uniform control flow; no block barriers.
__device__ __forceinline__ void wave_pick(const unsigned* region, int lane,
                                          unsigned rA, unsigned* slotA, bool doA,
                                          unsigned rB, unsigned* slotB, bool doB) {
    uint4 s = make_uint4(0u, 0u, 0u, 0u);
    #pragma unroll
    for (int r = 0; r < NREP; ++r) {
        uint4 h = ((const uint4*)(region + r * HSTRIDE))[lane];  // bins 4L..4L+3
        s.x += h.x; s.y += h.y; s.z += h.z; s.w += h.w;
    }
    unsigned lp0 = s.x, lp1 = lp0 + s.y, lp2 = lp1 + s.z, tot = lp2 + s.w;
    unsigned scan = tot;
    #pragma unroll
    for (int off = 1; off < 64; off <<= 1) {
        unsigned v = __shfl_up(scan, off, 64);
        if (lane >= off) scan += v;
    }
    unsigned ex = scan - tot;                    // exclusive base of this lane's 4 bins
    unsigned lpx[4] = {0u, lp0, lp1, lp2};
    unsigned cc[4]  = {s.x, s.y, s.z, s.w};
    if (doA && rA >= ex && rA < ex + tot) {
        #pragma unroll
        for (int j = 0; j < 4; ++j)
            if (rA >= ex + lpx[j] && rA < ex + lpx[j] + cc[j]) {
                slotA[0] = (unsigned)(4 * lane + j);
                slotA[1] = rA - ex - lpx[j];
            }
    }
    if (doB && rB >= ex && rB < ex + tot) {
        #pragma unroll
        for (int j = 0; j < 4; ++j)
            if (rB >= ex + lpx[j] && rB < ex + lpx[j] + cc[j]) {
                slotB[0] = (unsigned)(4 * lane + j);
                slotB[1] = rB - ex - lpx[j];
            }
    }
}

__global__ void __launch_bounds__(NTHREADS, 4)
xsrelu_kernel(const float* __restrict__ x, const float* __restrict__ plogit,
              float* __restrict__ out, int C) {
    __shared__ __align__(16) unsigned hist[4][WHSIZE];   // per-wave private, ~32.5 KiB
    __shared__ unsigned bcast[4][4];                     // per-wave {bA,nrA,bB,nrB}

    const int wave = threadIdx.x >> 6;
    const int lane = threadIdx.x & 63;
    const int row  = blockIdx.x * 4 + wave;              // one wave per row

    // Load row (coalesced float4); keys stay in registers.
    const float4* xr = (const float4*)(x + (size_t)row * NELEM);
    unsigned k[EPL];
    #pragma unroll
    for (int j = 0; j < EPL / 4; ++j) {
        float4 v = xr[j * 64 + lane];
        k[4 * j + 0] = f2ord(v.x);
        k[4 * j + 1] = f2ord(v.y);
        k[4 * j + 2] = f2ord(v.z);
        k[4 * j + 3] = f2ord(v.w);
    }

    // p0 -> scalar rank indices; pc -> interpolation weight.
    float p0 = 1.0f / (1.0f + expf(-plogit[0]));
    float pc = 1.0f / (1.0f + expf(-plogit[row % C]));
    int kLow  = min(max((int)((float)NELEM * (p0 - 0.02f)), 0), NELEM - 1);
    int kHigh = min(max((int)((float)NELEM * (p0 + 0.02f)), 0), NELEM - 1);

    unsigned* hw = hist[wave];
    unsigned* bc = bcast[wave];
    const int rep = lane & (NREP - 1);
    unsigned* myA = hw + rep * HSTRIDE;
    unsigned* myB = hw + REGION + rep * HSTRIDE;

    unsigned prefA = 0u, prefB = 0u, known = 0u;
    unsigned rA = (unsigned)kLow, rB = (unsigned)kHigh;
    bool same = true;   // ranks still share a prefix -> share histogram

    #pragma unroll 1
    for (int shift = 24; shift >= 0; shift -= 8) {
        // Zero histogram regions (b128 stores).
        uint4* hz = (uint4*)hw;
        for (int i = lane; i < WHSIZE / 4; i += 64) hz[i] = make_uint4(0u, 0u, 0u, 0u);
        __threadfence_block();

        // Histogram next digit among prefix-matching keys.
        if (same) {
            #pragma unroll 16
            for (int j = 0; j < EPL; ++j) {
                unsigned kk = k[j];
                if ((kk & known) == prefA)
                    atomicAdd(&myA[(kk >> shift) & 0xFFu], 1u);
            }
        } else {
            #pragma unroll 16
            for (int j = 0; j < EPL; ++j) {
                unsigned kk = k[j];
                unsigned m = kk & known;
                if (m == prefA) atomicAdd(&myA[(kk >> shift) & 0xFFu], 1u);
                if (m == prefB) atomicAdd(&myB[(kk >> shift) & 0xFFu], 1u);
            }
        }
        __threadfence_block();

        // Scan + pick (both ranks from region A while shared).
        wave_pick(hw, lane, rA, bc + 0, true, rB, bc + 2, same);
        if (!same)
            wave_pick(hw + REGION, lane, rB, bc + 2, true, 0u, bc + 2, false);
        __threadfence_block();

        unsigned bA = bc[0], nrA = bc[1], bB = bc[2], nrB = bc[3];
        prefA |= bA << shift;  rA = nrA;
        prefB |= bB << shift;  rB = nrB;
        same = same && (bA == bB);
        known |= 0xFFu << shift;
        __threadfence_block();   // bc reads drain before next pass reuses slots
    }

    float xlow  = ord2f(prefA);
    float xhigh = ord2f(prefB);
    float thr = xlow + (xhigh - xlow) * pc;

    // Epilogue: relu(x - thr) from register keys.
    float4* outr = (float4*)(out + (size_t)row * NELEM);
    #pragma unroll
    for (int j = 0; j < EPL / 4; ++j) {
        float4 o;
        o.x = fmaxf(ord2f(k[4 * j + 0]) - thr, 0.0f);
        o.y = fmaxf(ord2f(k[4 * j + 1]) - thr, 0.0f);
        o.z = fmaxf(ord2f(k[4 * j + 2]) - thr, 0.0f);
        o.w = fmaxf(ord2f(k[4 * j + 3]) - thr, 0.0f);
        outr[j * 64 + lane] = o;
    }
}

extern "C" void kernel_launch(void* const* d_in, const int* in_sizes, int n_in,
                              void* d_out, int out_size, void* d_ws, size_t ws_size,
                              hipStream_t stream) {
    const float* x      = (const float*)d_in[0];
    const float* plogit = (const float*)d_in[1];
    float* out          = (float*)d_out;
    int C    = in_sizes[1];              // 256
    int rows = in_sizes[0] / NELEM;      // 8192
    xsrelu_kernel<<<rows / 4, NTHREADS, 0, stream>>>(x, plogit, out, C);
}

// Round 4
// 271.727 us; speedup vs baseline: 1.4840x; 1.4840x over previous
//
#include <hip/hip_runtime.h>
#include <math.h>

#define NTHREADS 256
#define NELEM    4096            // H*W
#define EPL      64              // elements per lane (one wave per row)
#define NREP     8               // histogram replicas for shared (hot) passes
#define HSTRIDE  260             // %4==0 (uint4-aligned), %32==4 (replica bank spread)
#define WHSIZE   (NREP * HSTRIDE)   // 2080 uints = 8320 B per wave

// order-preserving float->uint map (ascending)
__device__ __forceinline__ unsigned f2ord(float f) {
    unsigned u = __float_as_uint(f);
    return (u & 0x80000000u) ? ~u : (u | 0x80000000u);
}
__device__ __forceinline__ float ord2f(unsigned k) {
    unsigned u = (k & 0x80000000u) ? (k ^ 0x80000000u) : ~k;
    return __uint_as_float(u);
}

__device__ __forceinline__ void zero_region(unsigned* h, int lane, int nuint4) {
    uint4* p = (uint4*)h;
    for (int i = lane; i < nuint4; i += 64) p[i] = make_uint4(0u, 0u, 0u, 0u);
}

// Histogram next radix digit among keys matching (key & known) == pref.
// FULLY UNROLLED: k[] must be statically indexed or it spills (R3 lesson).
template <int NR>
__device__ __forceinline__ void hist_pass(const unsigned* k, unsigned* h, int lane,
                                          unsigned known, unsigned pref, int shift) {
    unsigned* my = h + ((NR > 1) ? (lane & (NR - 1)) * HSTRIDE : 0);
    #pragma unroll
    for (int j = 0; j < EPL; ++j) {
        unsigned kk = k[j];
        if ((kk & known) == pref)
            atomicAdd(&my[(kk >> shift) & 0xFFu], 1u);
    }
}

struct Pick2 { unsigned a, b; };

// Reduce NR replicas of 256 bins (4 bins/lane), wave-scan, locate ranks rA,rB.
// Returns packed (bucket<<12)|newrank for each; wave-uniform via ballot+shfl.
template <int NR>
__device__ __forceinline__ Pick2 wave_pick2(const unsigned* region, int lane,
                                            unsigned rA, unsigned rB) {
    unsigned s0 = 0, s1 = 0, s2 = 0, s3 = 0;
    #pragma unroll
    for (int rep = 0; rep < NR; ++rep) {
        uint4 h = ((const uint4*)(region + rep * HSTRIDE))[lane];
        s0 += h.x; s1 += h.y; s2 += h.z; s3 += h.w;
    }
    unsigned lp1 = s0, lp2 = s0 + s1, lp3 = s0 + s1 + s2, tot = lp3 + s3;
    unsigned scan = tot;
    #pragma unroll
    for (int off = 1; off < 64; off <<= 1) {
        unsigned v = __shfl_up(scan, off, 64);
        if (lane >= off) scan += v;
    }
    unsigned ex = scan - tot;   // exclusive base of this lane's 4 bins
    unsigned base[4] = {ex, ex + lp1, ex + lp2, ex + lp3};
    unsigned cnt[4]  = {s0, s1, s2, s3};
    unsigned resA = 0, resB = 0;
    bool fA = false, fB = false;
    #pragma unroll
    for (int j = 0; j < 4; ++j) {
        if (rA >= base[j] && rA < base[j] + cnt[j]) {
            resA = ((unsigned)(4 * lane + j) << 12) | (rA - base[j]); fA = true;
        }
        if (rB >= base[j] && rB < base[j] + cnt[j]) {
            resB = ((unsigned)(4 * lane + j) << 12) | (rB - base[j]); fB = true;
        }
    }
    unsigned long long mA = __ballot(fA);
    unsigned long long mB = __ballot(fB);
    Pick2 r;
    r.a = __shfl(resA, (int)(__ffsll((long long)mA) - 1), 64);
    r.b = __shfl(resB, (int)(__ffsll((long long)mB) - 1), 64);
    return r;
}

__global__ void __launch_bounds__(NTHREADS, 4)
xsrelu_kernel(const float* __restrict__ x, const float* __restrict__ plogit,
              float* __restrict__ out, int C) {
    __shared__ __align__(16) unsigned hist[4][WHSIZE];   // ~33 KiB/block

    const int wave = threadIdx.x >> 6;
    const int lane = threadIdx.x & 63;
    const int row  = blockIdx.x * 4 + wave;              // one wave per row

    // Load row (coalesced float4); keys live in 64 VGPRs.
    const float4* xr = (const float4*)(x + (size_t)row * NELEM);
    unsigned k[EPL];
    #pragma unroll
    for (int j = 0; j < EPL / 4; ++j) {
        float4 v = xr[j * 64 + lane];
        k[4 * j + 0] = f2ord(v.x);
        k[4 * j + 1] = f2ord(v.y);
        k[4 * j + 2] = f2ord(v.z);
        k[4 * j + 3] = f2ord(v.w);
    }

    // p0 -> scalar rank indices; pc -> interpolation weight.
    float p0 = 1.0f / (1.0f + expf(-plogit[0]));
    float pc = 1.0f / (1.0f + expf(-plogit[row % C]));
    int kLow  = min(max((int)((float)NELEM * (p0 - 0.02f)), 0), NELEM - 1);
    int kHigh = min(max((int)((float)NELEM * (p0 + 0.02f)), 0), NELEM - 1);

    unsigned* hw = hist[wave];
    unsigned prefA = 0u, prefB = 0u, known = 0u;
    unsigned rA = (unsigned)kLow, rB = (unsigned)kHigh;
    int shift;
    bool diverged = false;

    // Shared passes (both ranks in same bucket so far): 8 replicas.
    #pragma unroll 1
    for (shift = 24; shift >= 0; shift -= 8) {
        if (diverged) break;
        zero_region(hw, lane, WHSIZE / 4);
        __threadfence_block();
        hist_pass<NREP>(k, hw, lane, known, prefA, shift);
        __threadfence_block();
        Pick2 p = wave_pick2<NREP>(hw, lane, rA, rB);
        unsigned bA = p.a >> 12, bB = p.b >> 12;
        prefA |= bA << shift;  rA = p.a & 0xFFFu;
        prefB |= bB << shift;  rB = p.b & 0xFFFu;
        known |= 0xFFu << shift;
        diverged = (bA != bB);
        __threadfence_block();
    }

    // Tail passes: single replica (few surviving keys).
    unsigned knownA = known, knownB = known;
    #pragma unroll 1
    for (int s = shift; s >= 0; s -= 8) {
        zero_region(hw, lane, (HSTRIDE + 3) / 4);
        __threadfence_block();
        hist_pass<1>(k, hw, lane, knownA, prefA, s);
        __threadfence_block();
        Pick2 p = wave_pick2<1>(hw, lane, rA, rA);
        prefA |= (p.a >> 12) << s;
        rA = p.a & 0xFFFu;
        knownA |= 0xFFu << s;
        __threadfence_block();
    }
    #pragma unroll 1
    for (int s = shift; s >= 0; s -= 8) {
        zero_region(hw, lane, (HSTRIDE + 3) / 4);
        __threadfence_block();
        hist_pass<1>(k, hw, lane, knownB, prefB, s);
        __threadfence_block();
        Pick2 p = wave_pick2<1>(hw, lane, rB, rB);
        prefB |= (p.a >> 12) << s;
        rB = p.a & 0xFFFu;
        knownB |= 0xFFu << s;
        __threadfence_block();
    }

    float xlow  = ord2f(prefA);
    float xhigh = ord2f(prefB);
    float thr = xlow + (xhigh - xlow) * pc;

    // Epilogue: relu(x - thr) reconstructed from register keys.
    float4* outr = (float4*)(out + (size_t)row * NELEM);
    #pragma unroll
    for (int j = 0; j < EPL / 4; ++j) {
        float4 o;
        o.x = fmaxf(ord2f(k[4 * j + 0]) - thr, 0.0f);
        o.y = fmaxf(ord2f(k[4 * j + 1]) - thr, 0.0f);
        o.z = fmaxf(ord2f(k[4 * j + 2]) - thr, 0.0f);
        o.w = fmaxf(ord2f(k[4 * j + 3]) - thr, 0.0f);
        outr[j * 64 + lane] = o;
    }
}

extern "C" void kernel_launch(void* const* d_in, const int* in_sizes, int n_in,
                              void* d_out, int out_size, void* d_ws, size_t ws_size,
                              hipStream_t stream) {
    const float* x      = (const float*)d_in[0];
    const float* plogit = (const float*)d_in[1];
    float* out          = (float*)d_out;
    int C    = in_sizes[1];              // 256
    int rows = in_sizes[0] / NELEM;      // 8192
    xsrelu_kernel<<<rows / 4, NTHREADS, 0, stream>>>(x, plogit, out, C);
}

// Round 5
// 270.517 us; speedup vs baseline: 1.4906x; 1.0045x over previous
//
#include <hip/hip_runtime.h>
#include <math.h>

#define NTHREADS 256
#define NELEM    4096            // H*W
#define EPL      64              // elements per lane (one wave per row)
#define NREP     8               // histogram replicas for shared (hot) passes
#define HSTRIDE  260             // %4==0 (uint4-aligned), %32==4 (replica bank spread)
#define WHSIZE   (NREP * HSTRIDE)   // 2080 uints = 8320 B per wave

// order-preserving float->uint map (ascending)
__device__ __forceinline__ unsigned f2ord(float f) {
    unsigned u = __float_as_uint(f);
    return (u & 0x80000000u) ? ~u : (u | 0x80000000u);
}
__device__ __forceinline__ float ord2f(unsigned k) {
    unsigned u = (k & 0x80000000u) ? (k ^ 0x80000000u) : ~k;
    return __uint_as_float(u);
}

__device__ __forceinline__ void zero_region(unsigned* h, int lane, int nuint4) {
    uint4* p = (uint4*)h;
    for (int i = lane; i < nuint4; i += 64) p[i] = make_uint4(0u, 0u, 0u, 0u);
}

// Histogram next radix digit among keys matching (key & known) == pref.
// FULLY UNROLLED: k[] statically indexed (R3 lesson). Predicated atomics get
// s_cbranch_execz, so all-inactive iterations skip the DS op.
template <int NR>
__device__ __forceinline__ void hist_pass(const unsigned* k, unsigned* h, int lane,
                                          unsigned known, unsigned pref, int shift) {
    unsigned* my = h + ((NR > 1) ? (lane & (NR - 1)) * HSTRIDE : 0);
    #pragma unroll
    for (int j = 0; j < EPL; ++j) {
        unsigned kk = k[j];
        if ((kk & known) == pref)
            atomicAdd(&my[(kk >> shift) & 0xFFu], 1u);
    }
}

struct Pick2 { unsigned a, b; };

// Reduce NR replicas of 256 bins (4 bins/lane), wave-scan, locate ranks rA,rB.
// Returns packed (bucket<<12)|newrank for each; wave-uniform via ballot+shfl.
template <int NR>
__device__ __forceinline__ Pick2 wave_pick2(const unsigned* region, int lane,
                                            unsigned rA, unsigned rB) {
    unsigned s0 = 0, s1 = 0, s2 = 0, s3 = 0;
    #pragma unroll
    for (int rep = 0; rep < NR; ++rep) {
        uint4 h = ((const uint4*)(region + rep * HSTRIDE))[lane];
        s0 += h.x; s1 += h.y; s2 += h.z; s3 += h.w;
    }
    unsigned lp1 = s0, lp2 = s0 + s1, lp3 = s0 + s1 + s2, tot = lp3 + s3;
    unsigned scan = tot;
    #pragma unroll
    for (int off = 1; off < 64; off <<= 1) {
        unsigned v = __shfl_up(scan, off, 64);
        if (lane >= off) scan += v;
    }
    unsigned ex = scan - tot;   // exclusive base of this lane's 4 bins
    unsigned base[4] = {ex, ex + lp1, ex + lp2, ex + lp3};
    unsigned cnt[4]  = {s0, s1, s2, s3};
    unsigned resA = 0, resB = 0;
    bool fA = false, fB = false;
    #pragma unroll
    for (int j = 0; j < 4; ++j) {
        if (rA >= base[j] && rA < base[j] + cnt[j]) {
            resA = ((unsigned)(4 * lane + j) << 12) | (rA - base[j]); fA = true;
        }
        if (rB >= base[j] && rB < base[j] + cnt[j]) {
            resB = ((unsigned)(4 * lane + j) << 12) | (rB - base[j]); fB = true;
        }
    }
    unsigned long long mA = __ballot(fA);
    unsigned long long mB = __ballot(fB);
    Pick2 r;
    r.a = __shfl(resA, (int)(__ffsll((long long)mA) - 1), 64);
    r.b = __shfl(resB, (int)(__ffsll((long long)mB) - 1), 64);
    return r;
}

// waves_per_eu(4,5): min 4 -> 128-VGPR budget; max 5 -> the backend's
// memory-bound occupancy-boost heuristic cannot shrink to 64 VGPR + spill
// (R4: VGPR_Count=64 with ~57 MB scratch traffic killed it).
__global__ void __attribute__((amdgpu_flat_work_group_size(256, 256),
                               amdgpu_waves_per_eu(4, 5)))
xsrelu_kernel(const float* __restrict__ x, const float* __restrict__ plogit,
              float* __restrict__ out, int C) {
    __shared__ __align__(16) unsigned hist[4][WHSIZE];   // ~33 KiB/block

    const int wave = threadIdx.x >> 6;
    const int lane = threadIdx.x & 63;
    const int row  = blockIdx.x * 4 + wave;              // one wave per row

    // Load row (coalesced float4); keys live in 64 VGPRs.
    const float4* xr = (const float4*)(x + (size_t)row * NELEM);
    unsigned k[EPL];
    #pragma unroll
    for (int j = 0; j < EPL / 4; ++j) {
        float4 v = xr[j * 64 + lane];
        k[4 * j + 0] = f2ord(v.x);
        k[4 * j + 1] = f2ord(v.y);
        k[4 * j + 2] = f2ord(v.z);
        k[4 * j + 3] = f2ord(v.w);
    }

    // p0 -> scalar rank indices; pc -> interpolation weight.
    float p0 = 1.0f / (1.0f + expf(-plogit[0]));
    float pc = 1.0f / (1.0f + expf(-plogit[row % C]));
    int kLow  = min(max((int)((float)NELEM * (p0 - 0.02f)), 0), NELEM - 1);
    int kHigh = min(max((int)((float)NELEM * (p0 + 0.02f)), 0), NELEM - 1);

    unsigned* hw = hist[wave];
    unsigned prefA = 0u, prefB = 0u, known = 0u;
    unsigned rA = (unsigned)kLow, rB = (unsigned)kHigh;
    int shift;
    bool diverged = false;

    // Shared passes (both ranks in same bucket so far): 8 replicas.
    #pragma unroll 1
    for (shift = 24; shift >= 0; shift -= 8) {
        if (diverged) break;
        zero_region(hw, lane, WHSIZE / 4);
        __threadfence_block();
        hist_pass<NREP>(k, hw, lane, known, prefA, shift);
        __threadfence_block();
        Pick2 p = wave_pick2<NREP>(hw, lane, rA, rB);
        unsigned bA = p.a >> 12, bB = p.b >> 12;
        prefA |= bA << shift;  rA = p.a & 0xFFFu;
        prefB |= bB << shift;  rB = p.b & 0xFFFu;
        known |= 0xFFu << shift;
        diverged = (bA != bB);
        __threadfence_block();
    }

    // Tail passes: single replica (few surviving keys; empty iters skipped).
    unsigned knownA = known, knownB = known;
    #pragma unroll 1
    for (int s = shift; s >= 0; s -= 8) {
        zero_region(hw, lane, (HSTRIDE + 3) / 4);
        __threadfence_block();
        hist_pass<1>(k, hw, lane, knownA, prefA, s);
        __threadfence_block();
        Pick2 p = wave_pick2<1>(hw, lane, rA, rA);
        prefA |= (p.a >> 12) << s;
        rA = p.a & 0xFFFu;
        knownA |= 0xFFu << s;
        __threadfence_block();
    }
    #pragma unroll 1
    for (int s = shift; s >= 0; s -= 8) {
        zero_region(hw, lane, (HSTRIDE + 3) / 4);
        __threadfence_block();
        hist_pass<1>(k, hw, lane, knownB, prefB, s);
        __threadfence_block();
        Pick2 p = wave_pick2<1>(hw, lane, rB, rB);
        prefB |= (p.a >> 12) << s;
        rB = p.a & 0xFFFu;
        knownB |= 0xFFu << s;
        __threadfence_block();
    }

    float xlow  = ord2f(prefA);
    float xhigh = ord2f(prefB);
    float thr = xlow + (xhigh - xlow) * pc;

    // Epilogue: relu(x - thr) reconstructed from register keys.
    float4* outr = (float4*)(out + (size_t)row * NELEM);
    #pragma unroll
    for (int j = 0; j < EPL / 4; ++j) {
        float4 o;
        o.x = fmaxf(ord2f(k[4 * j + 0]) - thr, 0.0f);
        o.y = fmaxf(ord2f(k[4 * j + 1]) - thr, 0.0f);
        o.z = fmaxf(ord2f(k[4 * j + 2]) - thr, 0.0f);
        o.w = fmaxf(ord2f(k[4 * j + 3]) - thr, 0.0f);
        outr[j * 64 + lane] = o;
    }
}

extern "C" void kernel_launch(void* const* d_in, const int* in_sizes, int n_in,
                              void* d_out, int out_size, void* d_ws, size_t ws_size,
                              hipStream_t stream) {
    const float* x      = (const float*)d_in[0];
    const float* plogit = (const float*)d_in[1];
    float* out          = (float*)d_out;
    int C    = in_sizes[1];              // 256
    int rows = in_sizes[0] / NELEM;      // 8192
    xsrelu_kernel<<<rows / 4, NTHREADS, 0, stream>>>(x, plogit, out, C);
}

// Round 6
// 238.993 us; speedup vs baseline: 1.6872x; 1.1319x over previous
//
#include <hip/hip_runtime.h>
#include <math.h>

#define NTHREADS 256
#define NELEM    4096              // H*W
#define EPL      32                // keys per lane: 2 waves per row -> fits 64 VGPRs, no spill
#define NREPA    8                 // replicas for main (A) region, 4 per wave
#define NREPB    2                 // replicas for post-divergence (B) region, 1 per wave
#define HSTRIDE  260               // %4==0 (uint4-aligned), %32==4 (replica bank spread)
#define ASIZE    (NREPA * HSTRIDE) // 2080 uints
#define BSIZE    (NREPB * HSTRIDE) // 520 uints
#define ROWLDS   (ASIZE + BSIZE)   // 2600 uints = 10400 B per row

// order-preserving float->uint map (ascending)
__device__ __forceinline__ unsigned f2ord(float f) {
    unsigned u = __float_as_uint(f);
    return (u & 0x80000000u) ? ~u : (u | 0x80000000u);
}
__device__ __forceinline__ float ord2f(unsigned k) {
    unsigned u = (k & 0x80000000u) ? (k ^ 0x80000000u) : ~k;
    return __uint_as_float(u);
}

struct Pick2 { unsigned a, b; };

// Reduce NR replicas of 256 bins (4 bins/lane), wave-scan, locate ranks rA,rB.
// Wave-uniform result, packed (bucket<<12)|newrank; ballot+shfl broadcast.
template <int NR>
__device__ __forceinline__ Pick2 wave_pick2(const unsigned* region, int lane,
                                            unsigned rA, unsigned rB) {
    unsigned s0 = 0, s1 = 0, s2 = 0, s3 = 0;
    #pragma unroll
    for (int rep = 0; rep < NR; ++rep) {
        uint4 h = ((const uint4*)(region + rep * HSTRIDE))[lane];
        s0 += h.x; s1 += h.y; s2 += h.z; s3 += h.w;
    }
    unsigned lp1 = s0, lp2 = s0 + s1, lp3 = s0 + s1 + s2, tot = lp3 + s3;
    unsigned scan = tot;
    #pragma unroll
    for (int off = 1; off < 64; off <<= 1) {
        unsigned v = __shfl_up(scan, off, 64);
        if (lane >= off) scan += v;
    }
    unsigned ex = scan - tot;   // exclusive base of this lane's 4 bins
    unsigned base[4] = {ex, ex + lp1, ex + lp2, ex + lp3};
    unsigned cnt[4]  = {s0, s1, s2, s3};
    unsigned resA = 0, resB = 0;
    bool fA = false, fB = false;
    #pragma unroll
    for (int j = 0; j < 4; ++j) {
        if (rA >= base[j] && rA < base[j] + cnt[j]) {
            resA = ((unsigned)(4 * lane + j) << 12) | (rA - base[j]); fA = true;
        }
        if (rB >= base[j] && rB < base[j] + cnt[j]) {
            resB = ((unsigned)(4 * lane + j) << 12) | (rB - base[j]); fB = true;
        }
    }
    unsigned long long mA = __ballot(fA);
    unsigned long long mB = __ballot(fB);
    Pick2 r;
    r.a = __shfl(resA, (int)(__ffsll((long long)mA) - 1), 64);
    r.b = __shfl(resB, (int)(__ffsll((long long)mB) - 1), 64);
    return r;
}

__global__ void __launch_bounds__(NTHREADS)
xsrelu_kernel(const float* __restrict__ x, const float* __restrict__ plogit,
              float* __restrict__ out, int C) {
    __shared__ __align__(16) unsigned hist[2][ROWLDS];   // 20.8 KiB: 2 rows/block

    const int wid   = threadIdx.x >> 6;   // 0..3
    const int lane  = threadIdx.x & 63;
    const int rhalf = wid & 1;            // which half-row this wave owns
    const int rloc  = wid >> 1;           // row within block
    const int row   = blockIdx.x * 2 + rloc;
    const int rlane = rhalf * 64 + lane;  // 0..127 within row

    // Load half-row (coalesced float4); 32 keys/lane live in VGPRs (no spill).
    const float4* xr = (const float4*)(x + (size_t)row * NELEM);
    unsigned k[EPL];
    #pragma unroll
    for (int j = 0; j < EPL / 4; ++j) {
        float4 v = xr[j * 128 + rlane];
        k[4 * j + 0] = f2ord(v.x);
        k[4 * j + 1] = f2ord(v.y);
        k[4 * j + 2] = f2ord(v.z);
        k[4 * j + 3] = f2ord(v.w);
    }

    // p0 -> scalar rank indices (same for all rows); pc -> interp weight.
    float p0 = 1.0f / (1.0f + expf(-plogit[0]));
    float pc = 1.0f / (1.0f + expf(-plogit[row % C]));
    int kLow  = min(max((int)((float)NELEM * (p0 - 0.02f)), 0), NELEM - 1);
    int kHigh = min(max((int)((float)NELEM * (p0 + 0.02f)), 0), NELEM - 1);

    unsigned* hA  = hist[rloc];
    unsigned* hB  = hA + ASIZE;
    unsigned* myA = hA + (rhalf * 4 + (lane & 3)) * HSTRIDE;  // 4 replicas/wave
    unsigned* myB = hB + rhalf * HSTRIDE;                     // 1 replica/wave

    unsigned prefA = 0u, prefB = 0u, known = 0u;
    unsigned rA = (unsigned)kLow, rB = (unsigned)kHigh;
    bool diverged = false;

    // Fixed 4 passes -> barrier count uniform across all waves/rows.
    #pragma unroll 1
    for (int shift = 24; shift >= 0; shift -= 8) {
        // Zero this row's regions (both waves cooperate).
        uint4* hz = (uint4*)hA;
        #pragma unroll 1
        for (int i = rlane; i < ROWLDS / 4; i += 128)
            hz[i] = make_uint4(0u, 0u, 0u, 0u);
        __syncthreads();

        // Histogram next digit among prefix-matching keys (fully unrolled).
        #pragma unroll
        for (int j = 0; j < EPL; ++j) {
            unsigned kk = k[j];
            if ((kk & known) == prefA)
                atomicAdd(&myA[(kk >> shift) & 0xFFu], 1u);
        }
        if (diverged) {    // row-uniform; barrier stays outside
            #pragma unroll
            for (int j = 0; j < EPL; ++j) {
                unsigned kk = k[j];
                if ((kk & known) == prefB)
                    atomicAdd(&myB[(kk >> shift) & 0xFFu], 1u);
            }
        }
        __syncthreads();

        // Each wave computes picks redundantly from the shared histogram.
        Pick2 p = wave_pick2<NREPA>(hA, lane, rA, diverged ? rA : rB);
        unsigned pA = p.a, pB = p.b;
        if (diverged)
            pB = wave_pick2<NREPB>(hB, lane, rB, rB).a;
        unsigned bA = pA >> 12, bB = pB >> 12;
        prefA |= bA << shift;  rA = pA & 0xFFFu;
        prefB |= bB << shift;  rB = pB & 0xFFFu;
        diverged = diverged || (bA != bB);
        known |= 0xFFu << shift;
        __syncthreads();   // picks read before next pass zeroes
    }

    float xlow  = ord2f(prefA);
    float xhigh = ord2f(prefB);
    float thr = xlow + (xhigh - xlow) * pc;

    // Epilogue: relu(x - thr) from register keys.
    float4* outr = (float4*)(out + (size_t)row * NELEM);
    #pragma unroll
    for (int j = 0; j < EPL / 4; ++j) {
        float4 o;
        o.x = fmaxf(ord2f(k[4 * j + 0]) - thr, 0.0f);
        o.y = fmaxf(ord2f(k[4 * j + 1]) - thr, 0.0f);
        o.z = fmaxf(ord2f(k[4 * j + 2]) - thr, 0.0f);
        o.w = fmaxf(ord2f(k[4 * j + 3]) - thr, 0.0f);
        outr[j * 128 + rlane] = o;
    }
}

extern "C" void kernel_launch(void* const* d_in, const int* in_sizes, int n_in,
                              void* d_out, int out_size, void* d_ws, size_t ws_size,
                              hipStream_t stream) {
    const float* x      = (const float*)d_in[0];
    const float* plogit = (const float*)d_in[1];
    float* out          = (float*)d_out;
    int C    = in_sizes[1];              // 256
    int rows = in_sizes[0] / NELEM;      // 8192
    xsrelu_kernel<<<rows / 2, NTHREADS, 0, stream>>>(x, plogit, out, C);
}

// Round 7
// 234.271 us; speedup vs baseline: 1.7212x; 1.0202x over previous
//
#include <hip/hip_runtime.h>
#include <math.h>

#define NTHREADS 128               // 2 waves = 1 row; barriers couple only 2 waves
#define NELEM    4096              // H*W
#define EPL      32                // keys per lane -> fits 64 VGPRs, no spill (R6 lesson)
#define NREP1    8                 // pass-1 replicas (hot bucket ~1100 keys)
#define HSTRIDE  260               // %4==0 (uint4-aligned), %32==4 (replica bank spread)
#define AREG     (NREP1 * HSTRIDE) // 2080 words
#define BREG     (2 * HSTRIDE)     // 520 words (post-divergence region, 1 replica/wave)
#define LDSW     (AREG + BREG)     // 2600 words = 10.4 KB/block

// order-preserving float->uint map (ascending)
__device__ __forceinline__ unsigned f2ord(float f) {
    unsigned u = __float_as_uint(f);
    return (u & 0x80000000u) ? ~u : (u | 0x80000000u);
}
__device__ __forceinline__ float ord2f(unsigned k) {
    unsigned u = (k & 0x80000000u) ? (k ^ 0x80000000u) : ~k;
    return __uint_as_float(u);
}

// Canonical GCN wave64 inclusive add-scan in the VALU pipe via DPP
// (row_shr 1/2/4/8 then row_bcast:15 rows{1,3}, row_bcast:31 rows{2,3}).
// Replaces 6 dependent ds_bpermute round-trips (~700 cyc) with ~12 VALU ops.
__device__ __forceinline__ unsigned iscan_dpp(unsigned v) {
    v += (unsigned)__builtin_amdgcn_update_dpp(0, (int)v, 0x111, 0xF, 0xF, false);
    v += (unsigned)__builtin_amdgcn_update_dpp(0, (int)v, 0x112, 0xF, 0xF, false);
    v += (unsigned)__builtin_amdgcn_update_dpp(0, (int)v, 0x114, 0xF, 0xF, false);
    v += (unsigned)__builtin_amdgcn_update_dpp(0, (int)v, 0x118, 0xF, 0xF, false);
    v += (unsigned)__builtin_amdgcn_update_dpp(0, (int)v, 0x142, 0xA, 0xF, false);
    v += (unsigned)__builtin_amdgcn_update_dpp(0, (int)v, 0x143, 0xC, 0xF, false);
    return v;
}

struct Pick2 { unsigned a, b; };

// Reduce NR replicas of 256 bins (4 bins/lane), DPP-scan, locate ranks rA,rB.
// Wave-uniform packed result (bucket<<12)|newrank via ballot + v_readlane.
template <int NR>
__device__ __forceinline__ Pick2 wave_pick2(const unsigned* region, int lane,
                                            unsigned rA, unsigned rB) {
    unsigned s0 = 0, s1 = 0, s2 = 0, s3 = 0;
    #pragma unroll
    for (int rep = 0; rep < NR; ++rep) {
        uint4 h = ((const uint4*)(region + rep * HSTRIDE))[lane];
        s0 += h.x; s1 += h.y; s2 += h.z; s3 += h.w;
    }
    unsigned tot = s0 + s1 + s2 + s3;
    unsigned inc = iscan_dpp(tot);
    unsigned ex  = inc - tot;          // exclusive base of this lane's 4 bins
    unsigned base[4] = {ex, ex + s0, ex + s0 + s1, ex + s0 + s1 + s2};
    unsigned cnt[4]  = {s0, s1, s2, s3};
    unsigned resA = 0, resB = 0;
    bool fA = false, fB = false;
    #pragma unroll
    for (int j = 0; j < 4; ++j) {
        if (rA >= base[j] && rA < base[j] + cnt[j]) {
            resA = ((unsigned)(4 * lane + j) << 12) | (rA - base[j]); fA = true;
        }
        if (rB >= base[j] && rB < base[j] + cnt[j]) {
            resB = ((unsigned)(4 * lane + j) << 12) | (rB - base[j]); fB = true;
        }
    }
    unsigned long long mA = __ballot(fA);
    unsigned long long mB = __ballot(fB);
    Pick2 r;
    r.a = (unsigned)__builtin_amdgcn_readlane((int)resA, (int)(__ffsll((long long)mA) - 1));
    r.b = (unsigned)__builtin_amdgcn_readlane((int)resB, (int)(__ffsll((long long)mB) - 1));
    return r;
}

__global__ void __launch_bounds__(NTHREADS)
xsrelu_kernel(const float* __restrict__ x, const float* __restrict__ plogit,
              float* __restrict__ out, int C) {
    __shared__ __align__(16) unsigned hist[LDSW];     // 10.4 KB: one row per block

    const int tid  = threadIdx.x;      // 0..127
    const int wid  = tid >> 6;         // 0..1
    const int lane = tid & 63;
    const int row  = blockIdx.x;

    // Load row (coalesced float4); 32 keys/lane in VGPRs (no spill).
    const float4* xr = (const float4*)(x + (size_t)row * NELEM);
    unsigned k[EPL];
    #pragma unroll
    for (int j = 0; j < EPL / 4; ++j) {
        float4 v = xr[j * 128 + tid];
        k[4 * j + 0] = f2ord(v.x);
        k[4 * j + 1] = f2ord(v.y);
        k[4 * j + 2] = f2ord(v.z);
        k[4 * j + 3] = f2ord(v.w);
    }

    // p0 -> scalar rank indices; pc -> interpolation weight.
    float p0 = 1.0f / (1.0f + expf(-plogit[0]));
    float pc = 1.0f / (1.0f + expf(-plogit[row % C]));
    int kLow  = min(max((int)((float)NELEM * (p0 - 0.02f)), 0), NELEM - 1);
    int kHigh = min(max((int)((float)NELEM * (p0 + 0.02f)), 0), NELEM - 1);

    unsigned* hA  = hist;
    unsigned* hB  = hist + AREG;
    unsigned* my1 = hA + (wid * 4 + (lane & 3)) * HSTRIDE;  // pass1: 4 replicas/wave
    unsigned* myT = hA + wid * HSTRIDE;                     // tail: replica = wid
    unsigned* myB = hB + wid * HSTRIDE;

    unsigned prefA = 0u, prefB = 0u, known = 0xFF000000u;
    unsigned rA, rB;
    bool diverged;

    // ---- Pass 1 (bits 31..24), 8 replicas. Each wave zeroes+hists only its
    // own replicas -> no barrier between zero and hist.
    {
        uint4* z = (uint4*)(hA + wid * 4 * HSTRIDE);        // own 1040 words
        #pragma unroll 1
        for (int i = lane; i < HSTRIDE; i += 64) z[i] = make_uint4(0u, 0u, 0u, 0u);
        #pragma unroll
        for (int j = 0; j < EPL; ++j)
            atomicAdd(&my1[k[j] >> 24], 1u);
        __syncthreads();
        Pick2 p = wave_pick2<NREP1>(hA, lane, (unsigned)kLow, (unsigned)kHigh);
        unsigned bA = p.a >> 12, bB = p.b >> 12;
        prefA = bA << 24;  rA = p.a & 0xFFFu;
        prefB = bB << 24;  rB = p.b & 0xFFFu;
        diverged = (bA != bB);
        __syncthreads();   // picks read before tail pass zeroes region A
    }

    // ---- Passes 2..4: 1 replica/wave (survivors ~1000 -> few per bin).
    #pragma unroll 1
    for (int shift = 16; shift >= 0; shift -= 8) {
        uint4* z = (uint4*)myT;
        #pragma unroll 1
        for (int i = lane; i < HSTRIDE / 4; i += 64) z[i] = make_uint4(0u, 0u, 0u, 0u);
        if (diverged) {   // row-uniform branch
            uint4* zb = (uint4*)myB;
            #pragma unroll 1
            for (int i = lane; i < HSTRIDE / 4; i += 64) zb[i] = make_uint4(0u, 0u, 0u, 0u);
        }
        #pragma unroll
        for (int j = 0; j < EPL; ++j) {
            unsigned kk = k[j];
            if ((kk & known) == prefA)
                atomicAdd(&myT[(kk >> shift) & 0xFFu], 1u);
        }
        if (diverged) {
            #pragma unroll
            for (int j = 0; j < EPL; ++j) {
                unsigned kk = k[j];
                if ((kk & known) == prefB)
                    atomicAdd(&myB[(kk >> shift) & 0xFFu], 1u);
            }
        }
        __syncthreads();
        Pick2 p = wave_pick2<2>(hA, lane, rA, diverged ? rA : rB);
        unsigned pA = p.a, pB = p.b;
        if (diverged)
            pB = wave_pick2<2>(hB, lane, rB, rB).a;
        unsigned bA = pA >> 12, bB = pB >> 12;
        prefA |= bA << shift;  rA = pA & 0xFFFu;
        prefB |= bB << shift;  rB = pB & 0xFFFu;
        diverged = diverged || (bA != bB);
        known |= 0xFFu << shift;
        __syncthreads();   // picks read before next pass zeroes
    }

    float xlow  = ord2f(prefA);
    float xhigh = ord2f(prefB);
    float thr = xlow + (xhigh - xlow) * pc;

    // Epilogue: relu(x - thr) from register keys.
    float4* outr = (float4*)(out + (size_t)row * NELEM);
    #pragma unroll
    for (int j = 0; j < EPL / 4; ++j) {
        float4 o;
        o.x = fmaxf(ord2f(k[4 * j + 0]) - thr, 0.0f);
        o.y = fmaxf(ord2f(k[4 * j + 1]) - thr, 0.0f);
        o.z = fmaxf(ord2f(k[4 * j + 2]) - thr, 0.0f);
        o.w = fmaxf(ord2f(k[4 * j + 3]) - thr, 0.0f);
        outr[j * 128 + tid] = o;
    }
}

extern "C" void kernel_launch(void* const* d_in, const int* in_sizes, int n_in,
                              void* d_out, int out_size, void* d_ws, size_t ws_size,
                              hipStream_t stream) {
    const float* x      = (const float*)d_in[0];
    const float* plogit = (const float*)d_in[1];
    float* out          = (float*)d_out;
    int C    = in_sizes[1];              // 256
    int rows = in_sizes[0] / NELEM;      // 8192
    xsrelu_kernel<<<rows, NTHREADS, 0, stream>>>(x, plogit, out, C);
}